// Round 11
// baseline (132.361 us; speedup 1.0000x reference)
//
#include <hip/hip_runtime.h>

#define KSZ   121
#define KMEAN 60
#define IMW   512
#define IMH   512
#define NPLANES 24   // 8 * 3

typedef float    f32x4 __attribute__((ext_vector_type(4)));
typedef float    f32x2 __attribute__((ext_vector_type(2)));
typedef int      i32x4 __attribute__((ext_vector_type(4)));
typedef unsigned u32x4 __attribute__((ext_vector_type(4)));
typedef __fp16   f16x2 __attribute__((ext_vector_type(2)));

// CK-style raw buffer intrinsics: HW bounds check returns 0 for OOB lanes.
__device__ f32x4 buf_load_x4(i32x4 srsrc, int voffset, int soffset, int aux)
    __asm("llvm.amdgcn.raw.buffer.load.v4f32");
__device__ unsigned buf_load_u32(i32x4 srsrc, int voffset, int soffset, int aux)
    __asm("llvm.amdgcn.raw.buffer.load.i32");
__device__ void buf_store_f32(float data, i32x4 srsrc, int voffset, int soffset, int aux)
    __asm("llvm.amdgcn.raw.buffer.store.f32");

// NOTE: SRD lives in SGPRs -> every input to make_srd MUST be wave-uniform.
// hblur invariant: rows handled by a wave must be wave-uniform (one SRD/row).
__device__ __forceinline__ i32x4 make_srd(const void* p, int bytes) {
    union { const void* p; unsigned u[2]; } a; a.p = p;
    i32x4 r;
    r.x = (int)__builtin_amdgcn_readfirstlane((int)a.u[0]);   // wave-uniform base
    r.y = (int)__builtin_amdgcn_readfirstlane((int)a.u[1]);
    r.z = bytes;          // num_records: OOB load -> 0, OOB store -> dropped
    r.w = 0x00020000;     // raw dword SRD word3 (gfx9/gfx950)
    return r;
}

// Clamp a possibly-wrapped-negative byte offset to a positive OOB value.
__device__ __forceinline__ int safev(int voff) {
    unsigned u = (unsigned)voff;
    return (int)(u < 0x7fff0000u ? u : 0x7fff0000u);   // one v_min_u32
}

union HU { unsigned u; f16x2 h; };

// unpack fp16 pair dword -> 2 fp32
__device__ __forceinline__ f32x2 h2unpk(unsigned u) {
    HU a; a.u = u;
    f32x2 r; r.x = (float)a.h.x; r.y = (float)a.h.y;
    return r;
}

// ---------------------------------------------------------------------------
// Kernel 1: taps w[0..120] (pad to 128 with 0) + edge-correction tables.
//   out[o] = sum_k w[k]*zpad[o+k-60] + edge0*L[o] + edgeN*R[o]
//   L[o] = P[59-o] (o<=59), R[o] = 1-P[571-o] (o>=452), P = prefix sum of w.
// ws: [0,128) taps, [128,640) L, [640,1152) R; fp16-pair tmp at byte 4608.
// (proven r5-r8 version)
// ---------------------------------------------------------------------------
__global__ __launch_bounds__(128) void weights_kernel(const float* __restrict__ sigma,
                                                      float* __restrict__ ws) {
    __shared__ float w[121];
    __shared__ float P[121];
    int t = threadIdx.x;
    float s = sigma[0] * 8.0f + 16.0f;
    float ninv = -1.0f / (2.0f * s * s);
    if (t < 121) { float d = (float)(t - KMEAN); w[t] = __expf(d * d * ninv); }
    __syncthreads();
    if (t == 0) {
        float sum = 0.f;
        for (int i = 0; i < 121; ++i) sum += w[i];
        float inv = 1.f / sum, run = 0.f;
        for (int i = 0; i < 121; ++i) { float wi = w[i] * inv; w[i] = wi; run += wi; P[i] = run; }
    }
    __syncthreads();
    ws[t] = (t < 121) ? w[t] : 0.f;                       // taps, 121..127 = 0
    #pragma unroll
    for (int j = 0; j < 4; ++j) {
        int o = t * 4 + j;
        ws[128 + o] = (o <= 59)  ? P[59 - o]          : 0.f;   // L
        ws[640 + o] = (o >= 452) ? (1.f - P[571 - o]) : 0.f;   // R
    }
}

// ---------------------------------------------------------------------------
// Kernel 2: horizontal pass — r10's proven row-pair body, K-loop ROLLED
// (#pragma unroll 3: ~240-inst body, I$-resident; full unroll was ~2.3k inst
// = streaming I-fetch). Two wave-uniform SRDs (rows 2p,2p+1), 8 outputs/row,
// per chunk: 2 buffer_load_dwordx4 + s_load_dwordx4 weights + 64 FMA.
// Epilogue: fp32 edge corrections, fp16 pair pack (lo=even row), b128 store.
// ---------------------------------------------------------------------------
__global__ __launch_bounds__(256) void hblur(const float* __restrict__ x,
                                             const float* __restrict__ ws,
                                             unsigned* __restrict__ tmpw) {
    const int tid  = threadIdx.x;
    const int t    = tid & 63;                      // output group: cols 8t..8t+7
    const int pair = blockIdx.x * 4 + (tid >> 6);   // row pair (rows 2p, 2p+1)

    const float* __restrict__ xr0 = x + (size_t)(2 * pair) * IMW;
    const float* __restrict__ xr1 = xr0 + IMW;
    const i32x4 srd0 = make_srd(xr0, IMW * 4);
    const i32x4 srd1 = make_srd(xr1, IMW * 4);
    const f32x4* __restrict__ w4 = (const f32x4*)ws;

    const int voff = 32 * t - 240;                  // byte offset of quad (2t-15)

    float a0=0.f,a1=0.f,a2=0.f,a3=0.f,a4=0.f,a5=0.f,a6=0.f,a7=0.f;
    float b0=0.f,b1=0.f,b2=0.f,b3=0.f,b4=0.f,b5=0.f,b6=0.f,b7=0.f;
    f32x4 A0 = buf_load_x4(srd0, safev(voff),      0, 0);
    f32x4 A1 = buf_load_x4(srd0, safev(voff + 16), 0, 0);
    f32x4 B0 = buf_load_x4(srd1, safev(voff),      0, 0);
    f32x4 B1 = buf_load_x4(srd1, safev(voff + 16), 0, 0);
    #pragma unroll 3
    for (int c = 0; c < 31; ++c) {                  // taps 4c..4c+3 (121..123 w=0)
        f32x4 A2 = buf_load_x4(srd0, safev(voff + 32 + 16 * c), 0, 0);
        f32x4 B2 = buf_load_x4(srd1, safev(voff + 32 + 16 * c), 0, 0);
        f32x4 w  = w4[c];                           // uniform -> s_load_dwordx4
        a0 += w.x*A0.x + w.y*A0.y + w.z*A0.z + w.w*A0.w;
        a1 += w.x*A0.y + w.y*A0.z + w.z*A0.w + w.w*A1.x;
        a2 += w.x*A0.z + w.y*A0.w + w.z*A1.x + w.w*A1.y;
        a3 += w.x*A0.w + w.y*A1.x + w.z*A1.y + w.w*A1.z;
        a4 += w.x*A1.x + w.y*A1.y + w.z*A1.z + w.w*A1.w;
        a5 += w.x*A1.y + w.y*A1.z + w.z*A1.w + w.w*A2.x;
        a6 += w.x*A1.z + w.y*A1.w + w.z*A2.x + w.w*A2.y;
        a7 += w.x*A1.w + w.y*A2.x + w.z*A2.y + w.w*A2.z;
        b0 += w.x*B0.x + w.y*B0.y + w.z*B0.z + w.w*B0.w;
        b1 += w.x*B0.y + w.y*B0.z + w.z*B0.w + w.w*B1.x;
        b2 += w.x*B0.z + w.y*B0.w + w.z*B1.x + w.w*B1.y;
        b3 += w.x*B0.w + w.y*B1.x + w.z*B1.y + w.w*B1.z;
        b4 += w.x*B1.x + w.y*B1.y + w.z*B1.z + w.w*B1.w;
        b5 += w.x*B1.y + w.y*B1.z + w.z*B1.w + w.w*B2.x;
        b6 += w.x*B1.z + w.y*B1.w + w.z*B2.x + w.w*B2.y;
        b7 += w.x*B1.w + w.y*B2.x + w.z*B2.y + w.w*B2.z;
        A0 = A1; A1 = A2; B0 = B1; B1 = B2;
    }

    // replicate-pad corrections (per row)
    const float x0a = xr0[0], xNa = xr0[IMW - 1];
    const float x0b = xr1[0], xNb = xr1[IMW - 1];
    const f32x4* __restrict__ L4 = (const f32x4*)(ws + 128);
    const f32x4* __restrict__ R4 = (const f32x4*)(ws + 640);
    f32x4 La = L4[2*t], Lb = L4[2*t+1], Ra = R4[2*t], Rb = R4[2*t+1];
    a0 += x0a*La.x + xNa*Ra.x;  a1 += x0a*La.y + xNa*Ra.y;
    a2 += x0a*La.z + xNa*Ra.z;  a3 += x0a*La.w + xNa*Ra.w;
    a4 += x0a*Lb.x + xNa*Rb.x;  a5 += x0a*Lb.y + xNa*Rb.y;
    a6 += x0a*Lb.z + xNa*Rb.z;  a7 += x0a*Lb.w + xNa*Rb.w;
    b0 += x0b*La.x + xNb*Ra.x;  b1 += x0b*La.y + xNb*Ra.y;
    b2 += x0b*La.z + xNb*Ra.z;  b3 += x0b*La.w + xNb*Ra.w;
    b4 += x0b*Lb.x + xNb*Rb.x;  b5 += x0b*Lb.y + xNb*Rb.y;
    b6 += x0b*Lb.z + xNb*Rb.z;  b7 += x0b*Lb.w + xNb*Rb.w;

    HU p0,p1,p2,p3,p4,p5,p6,p7;
    p0.h = __builtin_amdgcn_cvt_pkrtz(a0, b0);   // lo = even row, hi = odd row
    p1.h = __builtin_amdgcn_cvt_pkrtz(a1, b1);
    p2.h = __builtin_amdgcn_cvt_pkrtz(a2, b2);
    p3.h = __builtin_amdgcn_cvt_pkrtz(a3, b3);
    p4.h = __builtin_amdgcn_cvt_pkrtz(a4, b4);
    p5.h = __builtin_amdgcn_cvt_pkrtz(a5, b5);
    p6.h = __builtin_amdgcn_cvt_pkrtz(a6, b6);
    p7.h = __builtin_amdgcn_cvt_pkrtz(a7, b7);
    u32x4 s0; s0.x=p0.u; s0.y=p1.u; s0.z=p2.u; s0.w=p3.u;
    u32x4 s1; s1.x=p4.u; s1.y=p5.u; s1.z=p6.u; s1.w=p7.u;
    u32x4* __restrict__ o4 = (u32x4*)(tmpw + (size_t)pair * IMW);
    o4[2*t]     = s0;
    o4[2*t + 1] = s1;
}

// ---------------------------------------------------------------------------
// Kernel 3: vertical pass — r8's PROVEN compute pattern (f32 window, 4-tap
// chunks, rolling 4-scalar weight s_load) on the fp16-pair tmp, K-loop
// ROLLED (#pragma unroll 1: ~170-inst body). Thread = 1 col x VR=32 rows.
// Window W[36] f32 (rows r0-60+4c4 .. +35); refill 2 pair-dwords/chunk with
// a 2-chunk register prefetch carried across iterations. Pair index <0 or
// >255 -> SRD OOB -> 0 (zero-pad, proven r10); replicate restored by fp32
// Lh/Rh corrections (same fp32 taps as the conv -> identity exact).
// ---------------------------------------------------------------------------
#define VR 32
__global__ __launch_bounds__(256) void vblur(const unsigned* __restrict__ tmpw,
                                             const float* __restrict__ ws,
                                             float* __restrict__ out) {
    const int t      = threadIdx.x;                // 0..255
    const int b      = blockIdx.x;                 // 0..767
    const int plane  = b >> 5;
    const int within = b & 31;
    const int c      = (within & 1) * 256 + t;     // column 0..511
    const int r0     = (within >> 1) * VR;         // output rows r0..r0+31
    const int M0     = (r0 - KMEAN) >> 1;          // first pair index (may be <0)
    const int voff   = c * 4;

    const unsigned* __restrict__ tp = tmpw + (size_t)plane * (IMW * IMH / 2);
    float* __restrict__ op = out + (size_t)plane * (IMW * IMH);
    const i32x4 srdT = make_srd(tp, IMW * IMH * 2);   // fp16 plane: 512 KB
    const i32x4 srdO = make_srd(op, IMW * IMH * 4);
    const f32x4* __restrict__ w4 = (const f32x4*)ws;

    // prime window: pairs M0..M0+17 -> rows r0-60 .. r0-25 = W[0..35]
    float W[36];
    #pragma unroll
    for (int d = 0; d < 18; ++d) {
        f32x2 u = h2unpk(buf_load_u32(srdT, voff, (M0 + d) * (IMW * 4), 0));
        W[2*d] = u.x; W[2*d+1] = u.y;
    }
    // prefetch pipeline: q = pairs M0+18,19 (chunk 0 refill), r = M0+20,21
    unsigned q0 = buf_load_u32(srdT, voff, (M0 + 18) * (IMW * 4), 0);
    unsigned q1 = buf_load_u32(srdT, voff, (M0 + 19) * (IMW * 4), 0);
    unsigned rr0 = buf_load_u32(srdT, voff, (M0 + 20) * (IMW * 4), 0);
    unsigned rr1 = buf_load_u32(srdT, voff, (M0 + 21) * (IMW * 4), 0);

    float acc[VR];
    #pragma unroll
    for (int i = 0; i < VR; ++i) acc[i] = 0.f;

    // invariant at chunk c4: W[d] = row r0-60+4*c4+d; q = pairs M0+2*c4+18,19
    #pragma unroll 1
    for (int c4 = 0; c4 < 30; ++c4) {
        f32x4 w = w4[c4];                          // uniform -> s_load_dwordx4
        #pragma unroll
        for (int i = 0; i < VR; ++i)
            acc[i] += w.x*W[i] + w.y*W[i+1] + w.z*W[i+2] + w.w*W[i+3];
        #pragma unroll
        for (int d = 0; d < 32; ++d) W[d] = W[d + 4];
        f32x2 ua = h2unpk(q0), ub = h2unpk(q1);
        W[32] = ua.x; W[33] = ua.y; W[34] = ub.x; W[35] = ub.y;
        q0 = rr0; q1 = rr1;
        rr0 = buf_load_u32(srdT, voff, (M0 + 2*c4 + 22) * (IMW * 4), 0);
        rr1 = buf_load_u32(srdT, voff, (M0 + 2*c4 + 23) * (IMW * 4), 0);
    }
    {   // final chunk c4 = 30: taps 120..123 (121..123 are zero weights)
        f32x4 w = w4[30];
        #pragma unroll
        for (int i = 0; i < VR; ++i)
            acc[i] += w.x*W[i] + w.y*W[i+1] + w.z*W[i+2] + w.w*W[i+3];
    }

    // replicate-pad corrections: row 0 = lo(pair 0), row 511 = hi(pair 255)
    f32x2 e0 = h2unpk(buf_load_u32(srdT, voff, 0, 0));
    f32x2 eN = h2unpk(buf_load_u32(srdT, voff, (IMH / 2 - 1) * (IMW * 4), 0));
    const float T0 = e0.x, TN = eN.y;
    const float* __restrict__ Lf = ws + 128;
    const float* __restrict__ Rf = ws + 640;
    #pragma unroll
    for (int i = 0; i < VR; ++i) {
        float L = Lf[r0 + i], R = Rf[r0 + i];      // uniform -> s_load
        acc[i] += L * T0 + R * TN;
    }

    #pragma unroll
    for (int i = 0; i < VR; ++i)
        buf_store_f32(acc[i], srdO, voff, (r0 + i) * (IMW * 4), 0);
}

// ---------------------------------------------------------------------------
extern "C" void kernel_launch(void* const* d_in, const int* in_sizes, int n_in,
                              void* d_out, int out_size, void* d_ws, size_t ws_size,
                              hipStream_t stream) {
    const float* x     = (const float*)d_in[0];
    const float* sigma = (const float*)d_in[1];
    float* out = (float*)d_out;

    // ws: [0,128) taps, [128,640) Lh, [640,1152) Rh; fp16-pair tmp at byte 4608
    float* ws_f = (float*)d_ws;
    unsigned* tmpw = (unsigned*)((char*)d_ws + 4608);

    weights_kernel<<<1, 128, 0, stream>>>(sigma, ws_f);
    hblur<<<NPLANES * IMH / 8, 256, 0, stream>>>(x, ws_f, tmpw);
    vblur<<<NPLANES * (IMH / VR) * 2, 256, 0, stream>>>(tmpw, ws_f, out);
}